// Round 4
// baseline (202.831 us; speedup 1.0000x reference)
//
#include <hip/hip_runtime.h>
#include <math.h>

// ---------------------------------------------------------------------------
// TwoDimEquivalent: B=8192 independent nonlinear scans of length T=2048.
//  * gauss_int depends only on s = delta^2 -> float2 pair-LUT in LDS
//    (one ds_read_b64 per step; LUT = exact 64-pt GL sum, nodes via Newton).
//  * contraction ~0.93/step -> 16 chunks x 128 steps, 128-step warmup.
//  * u reads: nontemporal float4, register double-buffered (prefetch next
//    8-col group during compute). Keeps L2 free to merge z partial lines.
//  * z writes staged in LDS, flushed as 8-col segments; L2 merges to lines.
// R1 bug: grid expr evaluated to 256 -> half output missing (fixed: 512).
// R2: write path was 161 MB (2.4x) + exposed u latency -> NT loads + prefetch.
// R3 bug: __builtin_nontemporal_load rejects HIP_vector_type -> use ext_vector.
// ---------------------------------------------------------------------------

#define Bsz   8192
#define Tlen  2048
#define TP1   2049
#define NQ    64
#define NG    4097                // g sample points, s = j/64 on [0,64]
#define NTAB2 4096                // float2 pair entries
#define INV_H 64.0f
#define CHUNKS 16
#define CLEN  128
#define WARM  128
#define BLOCK 256
#define TSTEP 8
#define SIM_GRID 512              // 32 row-blocks * 16 chunks

#define WS_TAB 128                // scalar g table offset (floats) in d_ws

typedef float v4f __attribute__((ext_vector_type(4)));  // NT-load-compatible

// --------------------------- setup: build LUT ------------------------------
__global__ __launch_bounds__(256) void setup_kernel(float* __restrict__ ws,
                                                    float* __restrict__ out) {
    __shared__ float  fx[NQ], fw[NQ];
    __shared__ double inv[NQ + 1];
    const int tid = threadIdx.x;
    if (tid <= NQ) inv[tid] = (tid == 0) ? 0.0 : 1.0 / (double)tid;
    __syncthreads();
    if (tid < NQ) {
        // Newton on P_64: guess err ~3e-4 -> 3 updates reach ~1e-15,
        // 4th pass evaluates pp at converged z (no update).
        double z = cos(3.14159265358979323846 * (tid + 0.75) / (NQ + 0.5));
        double p1 = 1.0, p2 = 0.0, pp = 1.0;
        for (int it = 0; it < 4; ++it) {
            p1 = 1.0; p2 = 0.0;
            for (int j = 1; j <= NQ; ++j) {
                double p3 = p2; p2 = p1;
                p1 = ((2.0 * j - 1.0) * z * p2 - (j - 1.0) * p3) * inv[j];
            }
            pp = NQ * (z * p1 - p2) / (z * z - 1.0);
            if (it < 3) z -= p1 / pp;
        }
        double w  = 2.0 / ((1.0 - z * z) * pp * pp);
        double xs = z * 5.0;                       // node scaled to [-5,5]
        fx[tid] = (float)xs;                       // f32 cast, like reference
        fw[tid] = (float)(w * 5.0 * exp(-0.5 * xs * xs) * 0.3989422804014327);
    }
    __syncthreads();
    const int j = blockIdx.x * BLOCK + tid;        // grid 32x256 = 8192
    if (j < NG) {                                  // g(s_j), s_j = j/64
        const float d = sqrtf((float)j * (1.0f / INV_H));
        float acc = 0.0f;
        #pragma unroll 8
        for (int q = 0; q < NQ; ++q) {
            float t = tanhf(d * fx[q]);
            acc = fmaf(fw[q], 1.0f - t * t, acc);
        }
        ws[WS_TAB + j] = acc;
    }
    out[(size_t)j * TP1] = 0.0f;                   // z_hist[:,0] = 0
}

// ------------------------------ main scan ----------------------------------
__device__ __forceinline__ float step_one(float uu, float& k1, float& k2,
                                          float& v, const float2* s_tab) {
    float s   = fmaf(k1, k1, fmaf(k2, k2, uu * uu));      // delta^2
    float idx = fminf(s * INV_H, 4094.999f);
    int   i0  = (int)idx;
    float f   = idx - (float)i0;
    float2 g2 = s_tab[i0];                                // one ds_read_b64
    float g   = fmaf(f, g2.y - g2.x, g2.x);               // gauss_int
    float gv  = g * v;
    float nk1 = fmaf(k1, fmaf(0.2f, g, 0.8f), 0.10f * gv);
    float nk2 = fmaf(k2, fmaf(0.1f, g, 0.8f), 0.38f * gv);
    v  = fmaf(0.2f, uu - v, v);
    k1 = nk1; k2 = nk2;
    return fmaf(2.8f, nk1, -2.2f * nk2);
}

__global__ __launch_bounds__(BLOCK, 2) void sim_kernel(const float* __restrict__ u,
                                                       const float* __restrict__ ws,
                                                       float* __restrict__ out) {
    __shared__ float2 s_tab[NTAB2];                // 32 KB pair table
    __shared__ float2 s_u2[4][BLOCK];              // 8 KB, [t-pair][row]
    __shared__ float2 s_z2[4][BLOCK + 8];          // 8.25 KB (pad: flush conflicts)
    const int tid = threadIdx.x;

    {   // pair-table fill from scalar g[] in ws (coalesced float4 + 1 scalar)
        const float* g = ws + WS_TAB;
        #pragma unroll
        for (int i = 0; i < NTAB2 / (BLOCK * 4); ++i) {   // 4 iters
            int k = (i * BLOCK + tid) * 4;
            float4 a = *(const float4*)(g + k);
            float  b = g[k + 4];
            s_tab[k + 0] = make_float2(a.x, a.y);
            s_tab[k + 1] = make_float2(a.y, a.z);
            s_tab[k + 2] = make_float2(a.z, a.w);
            s_tab[k + 3] = make_float2(a.w, b);
        }
    }

    const int c    = blockIdx.x >> 5;              // chunk id (16)
    const int bb   = blockIdx.x & 31;              // row-block id (32)
    const int rowb = bb * BLOCK;
    const int t_out   = c * CLEN;                  // first owned step
    const int t_end   = t_out + CLEN;
    const int t_begin = (c == 0) ? 0 : (t_out - WARM);

    float k1 = 0.f, k2 = 0.f, v = 0.f, zp = 0.f;   // zp: z of previous step
    const int r1 = tid >> 1;
    const int h4 = (tid & 1) * 4;
    const int ph = (tid & 1) * 2;
    const float* zs = (const float*)s_z2;          // dword view, row stride 528
    const float* __restrict__ upb = u + (size_t)(rowb + r1) * Tlen + h4;

    // prime the register u-buffer (nontemporal: keep L2 for z-line merging)
    v4f Ua = __builtin_nontemporal_load((const v4f*)(upb + t_begin));
    v4f Ub = __builtin_nontemporal_load((const v4f*)(upb + t_begin + 128 * Tlen));

    for (int tb = t_begin; tb < t_end; tb += TSTEP) {
        __syncthreads();                           // (1) tiles free for reuse
        s_u2[ph    ][r1      ] = make_float2(Ua.x, Ua.y);
        s_u2[ph + 1][r1      ] = make_float2(Ua.z, Ua.w);
        s_u2[ph    ][r1 + 128] = make_float2(Ub.x, Ub.y);
        s_u2[ph + 1][r1 + 128] = make_float2(Ub.z, Ub.w);
        const int tn = tb + TSTEP;                 // prefetch next group
        if (tn < t_end) {
            Ua = __builtin_nontemporal_load((const v4f*)(upb + tn));
            Ub = __builtin_nontemporal_load((const v4f*)(upb + tn + 128 * Tlen));
        }
        __syncthreads();                           // (2) u tile ready
        const bool outg = (tb >= t_out);           // uniform per block
        #pragma unroll
        for (int p = 0; p < 4; ++p) {
            float2 uu = s_u2[p][tid];
            float za = step_one(uu.x, k1, k2, v, s_tab);
            float zb = step_one(uu.y, k1, k2, v, s_tab);
            // tile covers OUTPUT cols [tb, tb+8); col t+1 <- z of step t,
            // so slot 2p gets previous z, slot 2p+1 gets za; zb carries over.
            if (outg) s_z2[p][tid] = make_float2(zp, za);
            zp = zb;
        }
        if (outg) {
            __syncthreads();                       // (3) z tile complete
            const int r0   = tid >> 3;
            const int sf   = tid & 7;
            const int lofs = (sf >> 1) * 2 * (BLOCK + 8) + (sf & 1);
            if (tb == t_out) {                     // first group: col tb not ours
                if (sf != 0) {
                    #pragma unroll
                    for (int q = 0; q < 8; ++q) {
                        int r = r0 + 32 * q;
                        out[(size_t)(rowb + r) * TP1 + tb + sf] = zs[lofs + 2 * r];
                    }
                }
            } else {                               // full 8-col flush
                #pragma unroll
                for (int q = 0; q < 8; ++q) {
                    int r = r0 + 32 * q;
                    out[(size_t)(rowb + r) * TP1 + tb + sf] = zs[lofs + 2 * r];
                }
            }
        }
    }
    // last produced z (col t_end) never went through a tile
    out[(size_t)(rowb + tid) * TP1 + t_end] = zp;
}

// ------------------------------ launcher -----------------------------------
extern "C" void kernel_launch(void* const* d_in, const int* in_sizes, int n_in,
                              void* d_out, int out_size, void* d_ws, size_t ws_size,
                              hipStream_t stream) {
    const float* u = (const float*)d_in[0];
    float* out = (float*)d_out;
    float* ws  = (float*)d_ws;                     // needs ~17 KB
    setup_kernel<<<32, BLOCK, 0, stream>>>(ws, out);
    sim_kernel<<<SIM_GRID, BLOCK, 0, stream>>>(u, ws, out);
}

// Round 5
// 152.511 us; speedup vs baseline: 1.3299x; 1.3299x over previous
//
#include <hip/hip_runtime.h>
#include <math.h>

// ---------------------------------------------------------------------------
// TwoDimEquivalent: B=8192 independent nonlinear scans of length T=2048.
//  * gauss_int depends only on s = delta^2 -> float2 pair-LUT in LDS
//    (one ds_read_b64 per step; LUT = exact 64-pt GL sum, nodes via Newton).
//  * contraction ~0.93/step -> 16 chunks x 128 steps, 128-step warmup.
//  * u reads: plain float4 (LLC absorbs warmup re-reads), register prefetch.
//  * z output: 64 values per thread staged in REGISTERS, flushed per
//    half-chunk via 64x65 LDS transpose tile, per-wave 256 B contiguous
//    row-segment stores (odd stride 2049 prevents alignment; big segments
//    keep sectors full).
// R1: grid expr bug (256 vs 512). R2: 90 us, WRITE 161 MB (2.4x) partial-line
// amplification. R4: NT loads bypass LLC -> FETCH +80 MB, regressed; write
// amplification unchanged -> structural fix (this round).
// ---------------------------------------------------------------------------

#define Bsz   8192
#define Tlen  2048
#define TP1   2049
#define NQ    64
#define NG    2049                // scalar g samples, s = j/32 on [0,64]
#define NTAB2 2048                // float2 pair entries (16 KB)
#define INV_H 32.0f
#define CHUNKS 16
#define CLEN  128
#define WARM  128
#define BLOCK 256
#define SIM_GRID 512              // 32 row-blocks * 16 chunks

#define WS_TAB 128                // scalar g table offset (floats) in d_ws

// --------------------------- setup: build LUT ------------------------------
__global__ __launch_bounds__(256) void setup_kernel(float* __restrict__ ws,
                                                    float* __restrict__ out) {
    __shared__ float  fx[NQ], fw[NQ];
    __shared__ double inv[NQ + 1];
    const int tid = threadIdx.x;
    if (tid <= NQ) inv[tid] = (tid == 0) ? 0.0 : 1.0 / (double)tid;
    __syncthreads();
    if (tid < NQ) {
        // Newton on P_64: guess err ~3e-4 -> 3 updates reach ~1e-15,
        // 4th pass evaluates pp at converged z (no update).
        double z = cos(3.14159265358979323846 * (tid + 0.75) / (NQ + 0.5));
        double p1 = 1.0, p2 = 0.0, pp = 1.0;
        for (int it = 0; it < 4; ++it) {
            p1 = 1.0; p2 = 0.0;
            for (int j = 1; j <= NQ; ++j) {
                double p3 = p2; p2 = p1;
                p1 = ((2.0 * j - 1.0) * z * p2 - (j - 1.0) * p3) * inv[j];
            }
            pp = NQ * (z * p1 - p2) / (z * z - 1.0);
            if (it < 3) z -= p1 / pp;
        }
        double w  = 2.0 / ((1.0 - z * z) * pp * pp);
        double xs = z * 5.0;                       // node scaled to [-5,5]
        fx[tid] = (float)xs;                       // f32 cast, like reference
        fw[tid] = (float)(w * 5.0 * exp(-0.5 * xs * xs) * 0.3989422804014327);
    }
    __syncthreads();
    const int j = blockIdx.x * BLOCK + tid;        // grid 32x256 = 8192
    if (j < NG) {                                  // g(s_j), s_j = j/32
        const float d = sqrtf((float)j * (1.0f / INV_H));
        float acc = 0.0f;
        #pragma unroll 8
        for (int q = 0; q < NQ; ++q) {
            float t = tanhf(d * fx[q]);
            acc = fmaf(fw[q], 1.0f - t * t, acc);
        }
        ws[WS_TAB + j] = acc;
    }
    out[(size_t)j * TP1] = 0.0f;                   // z_hist[:,0] = 0
}

// ------------------------------ main scan ----------------------------------
__device__ __forceinline__ float step_one(float uu, float& k1, float& k2,
                                          float& v, const float2* s_tab) {
    float s   = fmaf(k1, k1, fmaf(k2, k2, uu * uu));      // delta^2
    float idx = fminf(s * INV_H, 2046.999f);
    int   i0  = (int)idx;
    float f   = idx - (float)i0;
    float2 g2 = s_tab[i0];                                // one ds_read_b64
    float g   = fmaf(f, g2.y - g2.x, g2.x);               // gauss_int
    float gv  = g * v;
    float nk1 = fmaf(k1, fmaf(0.2f, g, 0.8f), 0.10f * gv);
    float nk2 = fmaf(k2, fmaf(0.1f, g, 0.8f), 0.38f * gv);
    v  = fmaf(0.2f, uu - v, v);
    k1 = nk1; k2 = nk2;
    return fmaf(2.8f, nk1, -2.2f * nk2);
}

__global__ __launch_bounds__(BLOCK, 3) void sim_kernel(const float* __restrict__ u,
                                                       const float* __restrict__ ws,
                                                       float* __restrict__ out) {
    __shared__ float2 s_tab[NTAB2];                // 16 KB pair table
    __shared__ float2 s_u2[4][BLOCK];              // 8 KB, [t-pair][row]
    __shared__ float  s_zt[64 * 65];               // 16.64 KB transpose tile
    const int tid = threadIdx.x;

    {   // pair-table fill from scalar g[] in ws (coalesced float4 + 1 scalar)
        const float* g = ws + WS_TAB;
        #pragma unroll
        for (int i = 0; i < NTAB2 / (BLOCK * 4); ++i) {   // 2 iters
            int k = (i * BLOCK + tid) * 4;
            float4 a = *(const float4*)(g + k);
            float  b = g[k + 4];
            s_tab[k + 0] = make_float2(a.x, a.y);
            s_tab[k + 1] = make_float2(a.y, a.z);
            s_tab[k + 2] = make_float2(a.z, a.w);
            s_tab[k + 3] = make_float2(a.w, b);
        }
    }

    const int c    = blockIdx.x >> 5;              // chunk id (16)
    const int bb   = blockIdx.x & 31;              // row-block id (32)
    const int rowb = bb * BLOCK;
    const int t_out   = c * CLEN;                  // first owned step
    const int t_begin = (c == 0) ? 0 : (t_out - WARM);

    float k1 = 0.f, k2 = 0.f, v = 0.f;
    const int r1 = tid >> 1;
    const int h4 = (tid & 1) * 4;
    const int ph = (tid & 1) * 2;
    const float* __restrict__ upb = u + (size_t)(rowb + r1) * Tlen + h4;

    float4 Ua = *(const float4*)(upb + t_begin);
    float4 Ub = *(const float4*)(upb + t_begin + 128 * Tlen);

    // ---------------- warmup: state only, z discarded ----------------
    for (int tb = t_begin; tb < t_out; tb += 8) {
        __syncthreads();
        s_u2[ph    ][r1      ] = make_float2(Ua.x, Ua.y);
        s_u2[ph + 1][r1      ] = make_float2(Ua.z, Ua.w);
        s_u2[ph    ][r1 + 128] = make_float2(Ub.x, Ub.y);
        s_u2[ph + 1][r1 + 128] = make_float2(Ub.z, Ub.w);
        const int tn = tb + 8;                     // <= t_out <= 1920, in-bounds
        Ua = *(const float4*)(upb + tn);
        Ub = *(const float4*)(upb + tn + 128 * Tlen);
        __syncthreads();
        #pragma unroll
        for (int p = 0; p < 4; ++p) {
            float2 uu = s_u2[p][tid];
            step_one(uu.x, k1, k2, v, s_tab);
            step_one(uu.y, k1, k2, v, s_tab);
        }
    }

    // ---------------- output: two half-chunks of 64 steps ----------------
    const int myw = tid >> 6;                      // wave id (4)
    const int lr  = tid & 63;
    for (int h = 0; h < 2; ++h) {
        float zz[64];                              // this thread's 64 z values
        #pragma unroll
        for (int gq = 0; gq < 8; ++gq) {
            const int tb = t_out + h * 64 + gq * 8;
            __syncthreads();
            s_u2[ph    ][r1      ] = make_float2(Ua.x, Ua.y);
            s_u2[ph + 1][r1      ] = make_float2(Ua.z, Ua.w);
            s_u2[ph    ][r1 + 128] = make_float2(Ub.x, Ub.y);
            s_u2[ph + 1][r1 + 128] = make_float2(Ub.z, Ub.w);
            int tn = tb + 8;                       // clamp: last group of c=15
            if (tn > Tlen - 8) tn = Tlen - 8;
            Ua = *(const float4*)(upb + tn);
            Ub = *(const float4*)(upb + tn + 128 * Tlen);
            __syncthreads();
            #pragma unroll
            for (int p = 0; p < 4; ++p) {
                float2 uu = s_u2[p][tid];
                zz[gq * 8 + 2 * p    ] = step_one(uu.x, k1, k2, v, s_tab);
                zz[gq * 8 + 2 * p + 1] = step_one(uu.y, k1, k2, v, s_tab);
            }
        }
        // flush: 4 phases of 64 rows; per-wave stores = 256 B contiguous
        const int cb = t_out + 1 + h * 64;         // first output col
        for (int p4 = 0; p4 < 4; ++p4) {
            __syncthreads();                       // zt free
            if (myw == p4) {                       // wave p4 owns rows [64p4,64p4+64)
                #pragma unroll
                for (int j = 0; j < 64; ++j)       // banks (lr+j)%32: 2-way, free
                    s_zt[lr * 65 + j] = zz[j];
            }
            __syncthreads();                       // zt ready
            #pragma unroll
            for (int k = 0; k < 16; ++k) {
                int d   = tid + 256 * k;
                int row = d >> 6;
                int col = d & 63;
                out[(size_t)(rowb + p4 * 64 + row) * TP1 + cb + col] =
                    s_zt[row * 65 + col];
            }
        }
    }
}

// ------------------------------ launcher -----------------------------------
extern "C" void kernel_launch(void* const* d_in, const int* in_sizes, int n_in,
                              void* d_out, int out_size, void* d_ws, size_t ws_size,
                              hipStream_t stream) {
    const float* u = (const float*)d_in[0];
    float* out = (float*)d_out;
    float* ws  = (float*)d_ws;                     // needs ~9 KB
    setup_kernel<<<32, BLOCK, 0, stream>>>(ws, out);
    sim_kernel<<<SIM_GRID, BLOCK, 0, stream>>>(u, ws, out);
}